// Round 1
// baseline (36648.465 us; speedup 1.0000x reference)
//
#include <hip/hip_runtime.h>
#include <math.h>

#define Bn 64
#define Hn 1024
#define En 512
#define Sn 512
#define KT 128
#define KTP 132   // padded LDS stride (132 % 32 == 4 -> 2-way max aliasing, free)

// Per-step LSTM cell. Grid = 256 blocks (one per CU), block = 256 threads.
// Block owns hidden columns [4*blockIdx, 4*blockIdx+4) for all 4 gates and
// all 64 batches. Computes gate preacts = e_s @ Wx^T + h_prev @ Wh^T + b,
// then the cell update, writing h_out/c_out (double-buffered in ws).
__global__ __launch_bounds__(256) void lstm_step(
    const int* __restrict__ x, const float* __restrict__ emb,
    const float* __restrict__ Wxi, const float* __restrict__ Wxf,
    const float* __restrict__ Wxg, const float* __restrict__ Wxo,
    const float* __restrict__ bi, const float* __restrict__ bf,
    const float* __restrict__ bg, const float* __restrict__ bo,
    const float* __restrict__ Whi, const float* __restrict__ Whf,
    const float* __restrict__ Whg, const float* __restrict__ Who,
    const float* __restrict__ h_in, const float* __restrict__ c_in,
    float* __restrict__ h_out, float* __restrict__ c_out, int s)
{
    __shared__ float sh[Bn][KTP];   // staged e or h chunk, [batch][k]
    __shared__ float sw[16][KTP];   // staged weight rows, [gate*4 + j][k]

    const int tid = threadIdx.x;
    const int b   = tid >> 2;       // batch 0..63
    const int j   = tid & 3;        // column-within-block 0..3
    const int cb  = blockIdx.x * 4; // first hidden column of this block
    const int col = cb + j;

    float acc0 = 0.f, acc1 = 0.f, acc2 = 0.f, acc3 = 0.f;

    // ---- input part: K = 512 over e_s[b][:] = emb[x[b][s]][:] ----
    for (int k0 = 0; k0 < En; k0 += KT) {
        for (int i = tid; i < Bn * (KT / 4); i += 256) {
            int bl = i >> 5;              // i / 32
            int k4 = (i & 31) << 2;       // (i % 32) * 4
            int tok = x[bl * Sn + s];
            float4 v = *reinterpret_cast<const float4*>(
                &emb[(size_t)tok * En + k0 + k4]);
            *reinterpret_cast<float4*>(&sh[bl][k4]) = v;
        }
        for (int i = tid; i < 16 * (KT / 4); i += 256) {
            int r  = i >> 5;
            int k4 = (i & 31) << 2;
            const float* Wg = (r < 8) ? ((r < 4) ? Wxi : Wxf)
                                      : ((r < 12) ? Wxg : Wxo);
            int cr = cb + (r & 3);
            float4 v = *reinterpret_cast<const float4*>(
                &Wg[(size_t)cr * En + k0 + k4]);
            *reinterpret_cast<float4*>(&sw[r][k4]) = v;
        }
        __syncthreads();
        #pragma unroll 8
        for (int k = 0; k < KT; k += 4) {
            float4 hv = *reinterpret_cast<const float4*>(&sh[b][k]);
            float4 w0 = *reinterpret_cast<const float4*>(&sw[j][k]);
            float4 w1 = *reinterpret_cast<const float4*>(&sw[4 + j][k]);
            float4 w2 = *reinterpret_cast<const float4*>(&sw[8 + j][k]);
            float4 w3 = *reinterpret_cast<const float4*>(&sw[12 + j][k]);
            acc0 += hv.x*w0.x + hv.y*w0.y + hv.z*w0.z + hv.w*w0.w;
            acc1 += hv.x*w1.x + hv.y*w1.y + hv.z*w1.z + hv.w*w1.w;
            acc2 += hv.x*w2.x + hv.y*w2.y + hv.z*w2.z + hv.w*w2.w;
            acc3 += hv.x*w3.x + hv.y*w3.y + hv.z*w3.z + hv.w*w3.w;
        }
        __syncthreads();
    }

    // ---- recurrent part: K = 1024 over h_in[b][:] ----
    for (int k0 = 0; k0 < Hn; k0 += KT) {
        for (int i = tid; i < Bn * (KT / 4); i += 256) {
            int bl = i >> 5;
            int k4 = (i & 31) << 2;
            float4 v = *reinterpret_cast<const float4*>(
                &h_in[(size_t)bl * Hn + k0 + k4]);
            *reinterpret_cast<float4*>(&sh[bl][k4]) = v;
        }
        for (int i = tid; i < 16 * (KT / 4); i += 256) {
            int r  = i >> 5;
            int k4 = (i & 31) << 2;
            const float* Wg = (r < 8) ? ((r < 4) ? Whi : Whf)
                                      : ((r < 12) ? Whg : Who);
            int cr = cb + (r & 3);
            float4 v = *reinterpret_cast<const float4*>(
                &Wg[(size_t)cr * Hn + k0 + k4]);
            *reinterpret_cast<float4*>(&sw[r][k4]) = v;
        }
        __syncthreads();
        #pragma unroll 8
        for (int k = 0; k < KT; k += 4) {
            float4 hv = *reinterpret_cast<const float4*>(&sh[b][k]);
            float4 w0 = *reinterpret_cast<const float4*>(&sw[j][k]);
            float4 w1 = *reinterpret_cast<const float4*>(&sw[4 + j][k]);
            float4 w2 = *reinterpret_cast<const float4*>(&sw[8 + j][k]);
            float4 w3 = *reinterpret_cast<const float4*>(&sw[12 + j][k]);
            acc0 += hv.x*w0.x + hv.y*w0.y + hv.z*w0.z + hv.w*w0.w;
            acc1 += hv.x*w1.x + hv.y*w1.y + hv.z*w1.z + hv.w*w1.w;
            acc2 += hv.x*w2.x + hv.y*w2.y + hv.z*w2.z + hv.w*w2.w;
            acc3 += hv.x*w3.x + hv.y*w3.y + hv.z*w3.z + hv.w*w3.w;
        }
        __syncthreads();
    }

    // ---- cell update ----
    acc0 += bi[col];
    acc1 += bf[col];
    acc2 += bg[col];
    acc3 += bo[col];
    float it = 1.f / (1.f + expf(-acc0));
    float ft = 1.f / (1.f + expf(-acc1));
    float gt = tanhf(acc2);
    float ot = 1.f / (1.f + expf(-acc3));
    float cprev = c_in[b * Hn + col];
    float cn = ft * cprev + it * gt;
    float hn = ot * tanhf(cn);
    c_out[b * Hn + col] = cn;
    h_out[b * Hn + col] = hn;
}

// Copy final h, c into d_out[128..] layout: [out(128) | h(65536) | c(65536)]
__global__ __launch_bounds__(256) void copy_hc(
    const float* __restrict__ h, const float* __restrict__ c,
    float* __restrict__ out)
{
    int i = blockIdx.x * 256 + threadIdx.x;  // 0..65535
    out[128 + i] = h[i];
    out[128 + Bn * Hn + i] = c[i];
}

// logits[b][n] = h[b] . V_w[n] + V_b[n]; grid = 128 blocks (b*2+n), 64 lanes
__global__ __launch_bounds__(64) void classifier(
    const float* __restrict__ h, const float* __restrict__ Vw,
    const float* __restrict__ Vb, float* __restrict__ out)
{
    int bid = blockIdx.x;
    int b = bid >> 1;
    int n = bid & 1;
    int lane = threadIdx.x;
    float sum = 0.f;
    for (int k = lane; k < Hn; k += 64)
        sum += h[b * Hn + k] * Vw[n * Hn + k];
    #pragma unroll
    for (int off = 32; off > 0; off >>= 1)
        sum += __shfl_down(sum, off, 64);
    if (lane == 0)
        out[b * 2 + n] = sum + Vb[n];
}

extern "C" void kernel_launch(void* const* d_in, const int* in_sizes, int n_in,
                              void* d_out, int out_size, void* d_ws, size_t ws_size,
                              hipStream_t stream) {
    const int*   x   = (const int*)  d_in[0];
    const float* emb = (const float*)d_in[1];
    const float* Wxi = (const float*)d_in[2];
    const float* bi  = (const float*)d_in[3];
    const float* Whi = (const float*)d_in[4];
    const float* Wxf = (const float*)d_in[5];
    const float* bf  = (const float*)d_in[6];
    const float* Whf = (const float*)d_in[7];
    const float* Wxg = (const float*)d_in[8];
    const float* bg  = (const float*)d_in[9];
    const float* Whg = (const float*)d_in[10];
    const float* Wxo = (const float*)d_in[11];
    const float* bo  = (const float*)d_in[12];
    const float* Who = (const float*)d_in[13];
    const float* Vw  = (const float*)d_in[14];
    const float* Vb  = (const float*)d_in[15];
    float* out = (float*)d_out;

    float* hA = (float*)d_ws;
    float* cA = hA + Bn * Hn;
    float* hB = cA + Bn * Hn;
    float* cB = hB + Bn * Hn;

    // zero initial h0, c0 (hA, cA are contiguous)
    hipMemsetAsync(d_ws, 0, (size_t)2 * Bn * Hn * sizeof(float), stream);

    for (int s = 0; s < Sn; ++s) {
        const float* hi = (s & 1) ? hB : hA;
        const float* ci = (s & 1) ? cB : cA;
        float* ho = (s & 1) ? hA : hB;
        float* co = (s & 1) ? cA : cB;
        lstm_step<<<dim3(Hn / 4), dim3(256), 0, stream>>>(
            x, emb, Wxi, Wxf, Wxg, Wxo, bi, bf, bg, bo,
            Whi, Whf, Whg, Who, hi, ci, ho, co, s);
    }

    // S=512 is even: last step (s=511, odd) wrote into hA/cA
    copy_hc<<<dim3(Bn * Hn / 256), dim3(256), 0, stream>>>(hA, cA, out);
    classifier<<<dim3(Bn * 2), dim3(64), 0, stream>>>(hA, Vw, Vb, out);
}

// Round 2
// 30873.804 us; speedup vs baseline: 1.1870x; 1.1870x over previous
//
#include <hip/hip_runtime.h>
#include <math.h>

#define Bn 64
#define Hn 1024
#define En 512
#define Sn 512
#define NCOL 4096   // 4 gates * Hn
#define KTOT 1536   // Hn + En

// ======================= fast path kernels =======================

// ePack[(s*Bn+b)*En + k] = emb[x[b*Sn+s]*En + k]
__global__ __launch_bounds__(256) void epack_kernel(
    const int* __restrict__ x, const float* __restrict__ emb,
    float* __restrict__ ePack)
{
    int row = blockIdx.x * 2 + (threadIdx.x >> 7);   // 0..32767 = s*64+b
    int k4  = threadIdx.x & 127;                     // 128 float4 per row
    int s = row >> 6, b = row & 63;
    int tok = x[b * Sn + s];
    float4 v = ((const float4*)(emb + (size_t)tok * En))[k4];
    ((float4*)(ePack + (size_t)row * En))[k4] = v;
}

// wt[k4][col] (float4) = W^T[k4*4 .. k4*4+3][col]; k<1024 from Wh*, else Wx*
// col = gate*1024 + unit
__global__ __launch_bounds__(256) void wtpack_kernel(
    const float* __restrict__ Whi, const float* __restrict__ Whf,
    const float* __restrict__ Whg, const float* __restrict__ Who,
    const float* __restrict__ Wxi, const float* __restrict__ Wxf,
    const float* __restrict__ Wxg, const float* __restrict__ Wxo,
    float* __restrict__ wt)
{
    int idx = blockIdx.x * 256 + threadIdx.x;   // (k4,col): 384*4096
    int col = idx & (NCOL - 1);
    int k4  = idx >> 12;
    int gate = col >> 10, unit = col & 1023;
    const float* W;
    int kk;
    if (k4 < 256) {
        W = (gate == 0 ? Whi : gate == 1 ? Whf : gate == 2 ? Whg : Who)
            + (size_t)unit * Hn;
        kk = k4 * 4;
    } else {
        W = (gate == 0 ? Wxi : gate == 1 ? Wxf : gate == 2 ? Wxg : Wxo)
            + (size_t)unit * En;
        kk = (k4 - 256) * 4;
    }
    ((float4*)wt)[idx] = make_float4(W[kk], W[kk+1], W[kk+2], W[kk+3]);
}

__device__ __forceinline__ void loadrow(float4* dh, float4* de,
    const float* __restrict__ hrow, const float* __restrict__ erow)
{
    const float4* h4 = (const float4*)hrow;
    const float4* e4 = (const float4*)erow;
    #pragma unroll
    for (int j = 0; j < 8; ++j) dh[j] = h4[j];
    #pragma unroll
    for (int j = 0; j < 4; ++j) de[j] = e4[j];
}

__device__ __forceinline__ float dot12(const float4* wh, const float4* we,
                                       const float4* zh, const float4* ze)
{
    float a0 = 0.f, a1 = 0.f, a2 = 0.f, a3 = 0.f;
    #pragma unroll
    for (int j = 0; j < 8; ++j) {
        a0 += wh[j].x * zh[j].x; a1 += wh[j].y * zh[j].y;
        a2 += wh[j].z * zh[j].z; a3 += wh[j].w * zh[j].w;
    }
    #pragma unroll
    for (int j = 0; j < 4; ++j) {
        a0 += we[j].x * ze[j].x; a1 += we[j].y * ze[j].y;
        a2 += we[j].z * ze[j].z; a3 += we[j].w * ze[j].w;
    }
    return (a0 + a1) + (a2 + a3);
}

// Per-step fused projection: P[kp][b][col] = sum over this wave's k-slice of
// wT[k][col] * z[b][k], z = [h_prev | e_s]. Wave = (cg,kp): 64 cols, 32 h-k
// + 16 e-k. 512 blocks x 256 thr = 2048 waves = 2 waves/SIMD.
__global__ __launch_bounds__(256) void gemm_step(
    const float* __restrict__ wt, const float* __restrict__ hprev,
    const float* __restrict__ ePack, float* __restrict__ P, int s)
{
    const int wid = threadIdx.x >> 6, lane = threadIdx.x & 63;
    const int id  = blockIdx.x * 4 + wid;    // 0..2047
    const int cg  = id & 63, kp = id >> 6;   // kp 0..31
    const int col = cg * 64 + lane;

    const float4* wt4 = (const float4*)wt;
    float4 wh[8], we[4];
    #pragma unroll
    for (int j = 0; j < 8; ++j)
        wh[j] = wt4[(size_t)(kp * 8 + j) * NCOL + col];
    #pragma unroll
    for (int j = 0; j < 4; ++j)
        we[j] = wt4[(size_t)(256 + kp * 4 + j) * NCOL + col];

    const float* hbase = hprev + kp * 32;
    const float* ebase = ePack + (size_t)s * (Bn * En) + kp * 16;
    float* Pout = P + (size_t)kp * (Bn * NCOL) + col;

    float4 Ah[8], Ae[4], Bh[8], Be[4];
    loadrow(Ah, Ae, hbase, ebase);
    for (int b = 0; b < Bn; b += 2) {
        loadrow(Bh, Be, hbase + (size_t)(b + 1) * Hn,
                        ebase + (size_t)(b + 1) * En);
        Pout[(size_t)b * NCOL] = dot12(wh, we, Ah, Ae);
        if (b + 2 < Bn)
            loadrow(Ah, Ae, hbase + (size_t)(b + 2) * Hn,
                            ebase + (size_t)(b + 2) * En);
        Pout[(size_t)(b + 1) * NCOL] = dot12(wh, we, Bh, Be);
    }
}

// Reduce 32 partials + bias, apply LSTM cell, update h,c in place.
__global__ __launch_bounds__(256) void cell_step(
    const float* __restrict__ P,
    const float* __restrict__ bi, const float* __restrict__ bf,
    const float* __restrict__ bg, const float* __restrict__ bo,
    float* __restrict__ c, float* __restrict__ h)
{
    int t = blockIdx.x * 256 + threadIdx.x;  // 0..65535
    int b = t >> 10, u = t & 1023;
    const float* Pb = P + (size_t)b * NCOL;
    float si = bi[u], sf = bf[u], sg = bg[u], so = bo[u];
    #pragma unroll 4
    for (int kc = 0; kc < 32; ++kc) {
        const float* q = Pb + (size_t)kc * (Bn * NCOL);
        si += q[u];
        sf += q[1024 + u];
        sg += q[2048 + u];
        so += q[3072 + u];
    }
    float it = 1.f / (1.f + expf(-si));
    float ft = 1.f / (1.f + expf(-sf));
    float gt = tanhf(sg);
    float ot = 1.f / (1.f + expf(-so));
    float cn = ft * c[t] + it * gt;
    c[t] = cn;
    h[t] = ot * tanhf(cn);
}

// ======================= shared tail kernels =======================

__global__ __launch_bounds__(256) void copy_hc(
    const float* __restrict__ h, const float* __restrict__ c,
    float* __restrict__ out)
{
    int i = blockIdx.x * 256 + threadIdx.x;
    out[128 + i] = h[i];
    out[128 + Bn * Hn + i] = c[i];
}

__global__ __launch_bounds__(64) void classifier(
    const float* __restrict__ h, const float* __restrict__ Vw,
    const float* __restrict__ Vb, float* __restrict__ out)
{
    int bid = blockIdx.x;
    int b = bid >> 1, n = bid & 1;
    int lane = threadIdx.x;
    float sum = 0.f;
    for (int k = lane; k < Hn; k += 64)
        sum += h[b * Hn + k] * Vw[n * Hn + k];
    #pragma unroll
    for (int off = 32; off > 0; off >>= 1)
        sum += __shfl_down(sum, off, 64);
    if (lane == 0)
        out[b * 2 + n] = sum + Vb[n];
}

// ======================= fallback (round-1 proven path) =======================

#define KT 128
#define KTP 132

__global__ __launch_bounds__(256) void lstm_step_fb(
    const int* __restrict__ x, const float* __restrict__ emb,
    const float* __restrict__ Wxi, const float* __restrict__ Wxf,
    const float* __restrict__ Wxg, const float* __restrict__ Wxo,
    const float* __restrict__ bi, const float* __restrict__ bf,
    const float* __restrict__ bg, const float* __restrict__ bo,
    const float* __restrict__ Whi, const float* __restrict__ Whf,
    const float* __restrict__ Whg, const float* __restrict__ Who,
    const float* __restrict__ h_in, const float* __restrict__ c_in,
    float* __restrict__ h_out, float* __restrict__ c_out, int s)
{
    __shared__ float sh[Bn][KTP];
    __shared__ float sw[16][KTP];
    const int tid = threadIdx.x;
    const int b = tid >> 2, j = tid & 3;
    const int cb = blockIdx.x * 4, col = cb + j;
    float acc0 = 0.f, acc1 = 0.f, acc2 = 0.f, acc3 = 0.f;

    for (int k0 = 0; k0 < En; k0 += KT) {
        for (int i = tid; i < Bn * (KT / 4); i += 256) {
            int bl = i >> 5, k4 = (i & 31) << 2;
            int tok = x[bl * Sn + s];
            *reinterpret_cast<float4*>(&sh[bl][k4]) =
                *reinterpret_cast<const float4*>(&emb[(size_t)tok * En + k0 + k4]);
        }
        for (int i = tid; i < 16 * (KT / 4); i += 256) {
            int r = i >> 5, k4 = (i & 31) << 2;
            const float* Wg = (r < 8) ? ((r < 4) ? Wxi : Wxf)
                                      : ((r < 12) ? Wxg : Wxo);
            *reinterpret_cast<float4*>(&sw[r][k4]) =
                *reinterpret_cast<const float4*>(&Wg[(size_t)(cb + (r & 3)) * En + k0 + k4]);
        }
        __syncthreads();
        #pragma unroll 8
        for (int k = 0; k < KT; k += 4) {
            float4 hv = *reinterpret_cast<const float4*>(&sh[b][k]);
            float4 w0 = *reinterpret_cast<const float4*>(&sw[j][k]);
            float4 w1 = *reinterpret_cast<const float4*>(&sw[4 + j][k]);
            float4 w2 = *reinterpret_cast<const float4*>(&sw[8 + j][k]);
            float4 w3 = *reinterpret_cast<const float4*>(&sw[12 + j][k]);
            acc0 += hv.x*w0.x + hv.y*w0.y + hv.z*w0.z + hv.w*w0.w;
            acc1 += hv.x*w1.x + hv.y*w1.y + hv.z*w1.z + hv.w*w1.w;
            acc2 += hv.x*w2.x + hv.y*w2.y + hv.z*w2.z + hv.w*w2.w;
            acc3 += hv.x*w3.x + hv.y*w3.y + hv.z*w3.z + hv.w*w3.w;
        }
        __syncthreads();
    }
    for (int k0 = 0; k0 < Hn; k0 += KT) {
        for (int i = tid; i < Bn * (KT / 4); i += 256) {
            int bl = i >> 5, k4 = (i & 31) << 2;
            *reinterpret_cast<float4*>(&sh[bl][k4]) =
                *reinterpret_cast<const float4*>(&h_in[(size_t)bl * Hn + k0 + k4]);
        }
        for (int i = tid; i < 16 * (KT / 4); i += 256) {
            int r = i >> 5, k4 = (i & 31) << 2;
            const float* Wg = (r < 8) ? ((r < 4) ? Whi : Whf)
                                      : ((r < 12) ? Whg : Who);
            *reinterpret_cast<float4*>(&sw[r][k4]) =
                *reinterpret_cast<const float4*>(&Wg[(size_t)(cb + (r & 3)) * Hn + k0 + k4]);
        }
        __syncthreads();
        #pragma unroll 8
        for (int k = 0; k < KT; k += 4) {
            float4 hv = *reinterpret_cast<const float4*>(&sh[b][k]);
            float4 w0 = *reinterpret_cast<const float4*>(&sw[j][k]);
            float4 w1 = *reinterpret_cast<const float4*>(&sw[4 + j][k]);
            float4 w2 = *reinterpret_cast<const float4*>(&sw[8 + j][k]);
            float4 w3 = *reinterpret_cast<const float4*>(&sw[12 + j][k]);
            acc0 += hv.x*w0.x + hv.y*w0.y + hv.z*w0.z + hv.w*w0.w;
            acc1 += hv.x*w1.x + hv.y*w1.y + hv.z*w1.z + hv.w*w1.w;
            acc2 += hv.x*w2.x + hv.y*w2.y + hv.z*w2.z + hv.w*w2.w;
            acc3 += hv.x*w3.x + hv.y*w3.y + hv.z*w3.z + hv.w*w3.w;
        }
        __syncthreads();
    }
    acc0 += bi[col]; acc1 += bf[col]; acc2 += bg[col]; acc3 += bo[col];
    float it = 1.f / (1.f + expf(-acc0));
    float ft = 1.f / (1.f + expf(-acc1));
    float gt = tanhf(acc2);
    float ot = 1.f / (1.f + expf(-acc3));
    float cn = ft * c_in[b * Hn + col] + it * gt;
    c_out[b * Hn + col] = cn;
    h_out[b * Hn + col] = ot * tanhf(cn);
}

// ======================= launcher =======================

extern "C" void kernel_launch(void* const* d_in, const int* in_sizes, int n_in,
                              void* d_out, int out_size, void* d_ws, size_t ws_size,
                              hipStream_t stream) {
    const int*   x   = (const int*)  d_in[0];
    const float* emb = (const float*)d_in[1];
    const float* Wxi = (const float*)d_in[2];
    const float* bi  = (const float*)d_in[3];
    const float* Whi = (const float*)d_in[4];
    const float* Wxf = (const float*)d_in[5];
    const float* bf  = (const float*)d_in[6];
    const float* Whf = (const float*)d_in[7];
    const float* Wxg = (const float*)d_in[8];
    const float* bg  = (const float*)d_in[9];
    const float* Whg = (const float*)d_in[10];
    const float* Wxo = (const float*)d_in[11];
    const float* bo  = (const float*)d_in[12];
    const float* Who = (const float*)d_in[13];
    const float* Vw  = (const float*)d_in[14];
    const float* Vb  = (const float*)d_in[15];
    float* out = (float*)d_out;

    const size_t szHC    = (size_t)Bn * Hn * sizeof(float);      // 256 KB
    const size_t szEPack = (size_t)Sn * Bn * En * sizeof(float); // 64 MB
    const size_t szWt    = (size_t)KTOT * NCOL * sizeof(float);  // 24 MB
    const size_t szP     = (size_t)32 * Bn * NCOL * sizeof(float); // 32 MB
    const size_t need    = 2 * szHC + szEPack + szWt + szP;

    if (ws_size >= need) {
        float* h     = (float*)d_ws;
        float* c     = h + Bn * Hn;
        float* ePack = c + Bn * Hn;
        float* wt    = ePack + (size_t)Sn * Bn * En;
        float* P     = wt + (size_t)KTOT * NCOL;

        hipMemsetAsync(d_ws, 0, 2 * szHC, stream);
        epack_kernel<<<dim3(16384), dim3(256), 0, stream>>>(x, emb, ePack);
        wtpack_kernel<<<dim3(6144), dim3(256), 0, stream>>>(
            Whi, Whf, Whg, Who, Wxi, Wxf, Wxg, Wxo, wt);

        for (int s = 0; s < Sn; ++s) {
            gemm_step<<<dim3(512), dim3(256), 0, stream>>>(wt, h, ePack, P, s);
            cell_step<<<dim3(256), dim3(256), 0, stream>>>(P, bi, bf, bg, bo, c, h);
        }
        copy_hc<<<dim3(Bn * Hn / 256), dim3(256), 0, stream>>>(h, c, out);
        classifier<<<dim3(Bn * 2), dim3(64), 0, stream>>>(h, Vw, Vb, out);
    } else {
        // fallback: round-1 proven path (needs 1 MB of ws)
        float* hA = (float*)d_ws;
        float* cA = hA + Bn * Hn;
        float* hB = cA + Bn * Hn;
        float* cB = hB + Bn * Hn;
        hipMemsetAsync(d_ws, 0, 2 * szHC, stream);
        for (int s = 0; s < Sn; ++s) {
            const float* hi = (s & 1) ? hB : hA;
            const float* ci = (s & 1) ? cB : cA;
            float* ho = (s & 1) ? hA : hB;
            float* co = (s & 1) ? cA : cB;
            lstm_step_fb<<<dim3(Hn / 4), dim3(256), 0, stream>>>(
                x, emb, Wxi, Wxf, Wxg, Wxo, bi, bf, bg, bo,
                Whi, Whf, Whg, Who, hi, ci, ho, co, s);
        }
        copy_hc<<<dim3(Bn * Hn / 256), dim3(256), 0, stream>>>(hA, cA, out);
        classifier<<<dim3(Bn * 2), dim3(64), 0, stream>>>(hA, Vw, Vb, out);
    }
}

// Round 3
// 8320.602 us; speedup vs baseline: 4.4045x; 3.7105x over previous
//
#include <hip/hip_runtime.h>
#include <math.h>

#define Bn 64
#define Hn 1024
#define En 512
#define Sn 512

typedef _Float16 f16;
typedef _Float16 half8 __attribute__((ext_vector_type(8)));
typedef float f32x4 __attribute__((ext_vector_type(4)));

// ============================================================================
// Fragment layouts (gfx950 mfma_f32_16x16x32, HW-verified mappings):
//   A[m][k]: m = lane&15, k = (lane>>4)*8 + j   (8 f16 per lane = 16B)
//   B[k][n]: n = lane&15, k = (lane>>4)*8 + j
//   C/D[m][n]: n = lane&15, m = (lane>>4)*4 + reg
//
// zFrag (A-side, f16): index ((kc*4 + mt)*64 + lane), 8 halves each.
//   value = z[b = mt*16 + (lane&15)][k = kc*32 + (lane>>4)*8 + j]
//   kc 0..31 -> h part (k<1024), kc 32..47 -> e part (per-step eFrag).
// wPack (B-side, f16 hi + lo*2048): index ((g*64+bb)*48 + kc)*64 + lane.
//   value = W_g[u = bb*16 + (lane&15)][k], k = kc*32 + (lane>>4)*8 + j
//   (k<1024: W_h*, else W_x*[k-1024])
// ============================================================================

// ---- pack weights into B-fragment layout, fp16 hi/lo split ----
__global__ __launch_bounds__(256) void wpack_kernel(
    const float* __restrict__ Whi_, const float* __restrict__ Whf_,
    const float* __restrict__ Whg_, const float* __restrict__ Who_,
    const float* __restrict__ Wxi_, const float* __restrict__ Wxf_,
    const float* __restrict__ Wxg_, const float* __restrict__ Wxo_,
    f16* __restrict__ wHi, f16* __restrict__ wLo)
{
    int t = blockIdx.x * 256 + threadIdx.x;       // 786432 = 4*64*48*64
    int lane = t & 63;
    int rest = t >> 6;
    int kc = rest % 48;
    int gbb = rest / 48;
    int g = gbb >> 6, bb = gbb & 63;
    int u = bb * 16 + (lane & 15);
    int k = kc * 32 + ((lane >> 4) << 3);
    const float* Wh = (g == 0 ? Whi_ : g == 1 ? Whf_ : g == 2 ? Whg_ : Who_);
    const float* Wx = (g == 0 ? Wxi_ : g == 1 ? Wxf_ : g == 2 ? Wxg_ : Wxo_);
    const float* src = (k < Hn) ? (Wh + (size_t)u * Hn + k)
                                : (Wx + (size_t)u * En + (k - Hn));
    float4 v0 = ((const float4*)src)[0];
    float4 v1 = ((const float4*)src)[1];
    float w[8] = {v0.x, v0.y, v0.z, v0.w, v1.x, v1.y, v1.z, v1.w};
    #pragma unroll
    for (int j = 0; j < 8; ++j) {
        f16 hi = (f16)w[j];
        float lo = (w[j] - (float)hi) * 2048.0f;
        wHi[(size_t)t * 8 + j] = hi;
        wLo[(size_t)t * 8 + j] = (f16)lo;
    }
}

// ---- pack embedding gathers for ALL steps into A-fragment layout ----
__global__ __launch_bounds__(256) void epack_kernel(
    const int* __restrict__ x, const float* __restrict__ emb,
    f16* __restrict__ eF)
{
    int t = blockIdx.x * 256 + threadIdx.x;   // 2097152 = 512*16*4*64
    int lane = t & 63;
    int q = t >> 6;
    int mt = q & 3; q >>= 2;
    int kc2 = q & 15;
    int s = q >> 4;
    int b = mt * 16 + (lane & 15);
    int tok = x[b * Sn + s];
    int k = kc2 * 32 + ((lane >> 4) << 3);
    const float* src = emb + (size_t)tok * En + k;
    float4 v0 = ((const float4*)src)[0];
    float4 v1 = ((const float4*)src)[1];
    f16* dst = eF + (size_t)t * 8;
    dst[0] = (f16)v0.x; dst[1] = (f16)v0.y; dst[2] = (f16)v0.z; dst[3] = (f16)v0.w;
    dst[4] = (f16)v1.x; dst[5] = (f16)v1.y; dst[6] = (f16)v1.z; dst[7] = (f16)v1.w;
}

// ---- fused per-step kernel: MFMA GEMM (M=64,N=256 gate-cols per... ) + cell ----
// grid 64 blocks x 512 threads. Block bb owns units [bb*16, bb*16+16) for all
// 4 gates. Waves: wv = gate(0..3) | khalf<<2. Full K=1536 per block -> no
// global partials; cell fused via LDS.
__global__ __launch_bounds__(512) void step_kernel(
    const half8* __restrict__ hFin, f16* __restrict__ hFout,
    const half8* __restrict__ eF,
    const half8* __restrict__ wHi, const half8* __restrict__ wLo,
    const float* __restrict__ bi, const float* __restrict__ bf,
    const float* __restrict__ bg, const float* __restrict__ bo,
    float* __restrict__ c, float* __restrict__ hOut, int s)
{
    __shared__ float pre[2][4][64][16];   // [khalf][gate][batch][unit] = 32 KB

    const int tid  = threadIdx.x;
    const int lane = tid & 63;
    const int wv   = tid >> 6;
    const int g    = wv & 3;
    const int kh   = wv >> 2;
    const int bb   = blockIdx.x;

    f32x4 aH[4], aL[4];
    #pragma unroll
    for (int mt = 0; mt < 4; ++mt) { aH[mt] = (f32x4)0.0f; aL[mt] = (f32x4)0.0f; }

    const half8* eFs    = eF  + (size_t)s * (16 * 4 * 64);
    const half8* bHbase = wHi + ((size_t)(g * 64 + bb) * 48) * 64 + lane;
    const half8* bLbase = wLo + ((size_t)(g * 64 + bb) * 48) * 64 + lane;

    const int kc0 = kh * 24, kc1 = kc0 + 24;
    for (int kc = kc0; kc < kc1; ++kc) {
        half8 bh = bHbase[(size_t)kc * 64];
        half8 bl = bLbase[(size_t)kc * 64];
        const half8* aBase = (kc < 32)
            ? (hFin + (size_t)(kc * 4) * 64 + lane)
            : (eFs  + (size_t)((kc - 32) * 4) * 64 + lane);
        #pragma unroll
        for (int mt = 0; mt < 4; ++mt) {
            half8 a = aBase[(size_t)mt * 64];
            aH[mt] = __builtin_amdgcn_mfma_f32_16x16x32_f16(a, bh, aH[mt], 0, 0, 0);
            aL[mt] = __builtin_amdgcn_mfma_f32_16x16x32_f16(a, bl, aL[mt], 0, 0, 0);
        }
    }

    // epilogue: stash preact tiles; D row = (lane>>4)*4 + r, col = lane&15
    #pragma unroll
    for (int mt = 0; mt < 4; ++mt) {
        #pragma unroll
        for (int r = 0; r < 4; ++r) {
            int bidx = mt * 16 + ((lane >> 4) << 2) + r;
            pre[kh][g][bidx][lane & 15] = aH[mt][r] + aL[mt][r] * (1.0f / 2048.0f);
        }
    }
    __syncthreads();

    // cell update: 1024 outputs (64 batches x 16 units), 512 threads x 2
    #pragma unroll
    for (int t = tid; t < 1024; t += 512) {
        int b = t >> 4, u = t & 15;
        int col = bb * 16 + u;
        float si = pre[0][0][b][u] + pre[1][0][b][u] + bi[col];
        float sf = pre[0][1][b][u] + pre[1][1][b][u] + bf[col];
        float sg = pre[0][2][b][u] + pre[1][2][b][u] + bg[col];
        float so = pre[0][3][b][u] + pre[1][3][b][u] + bo[col];
        float it = 1.f / (1.f + expf(-si));
        float ft = 1.f / (1.f + expf(-sf));
        float gt = tanhf(sg);
        float ot = 1.f / (1.f + expf(-so));
        int gi = b * Hn + col;
        float cn = ft * c[gi] + it * gt;
        c[gi] = cn;
        float hn = ot * tanhf(cn);
        hOut[gi] = hn;
        // scatter into next step's A-frag layout: k = col
        int kc = col >> 5, dk = col & 31;
        int lp = ((dk >> 3) << 4) | (b & 15);
        int mtp = b >> 4;
        hFout[((size_t)(kc * 4 + mtp) * 64 + lp) * 8 + (dk & 7)] = (f16)hn;
    }
}

// ---- tail ----
__global__ __launch_bounds__(256) void copy_hc(
    const float* __restrict__ h, const float* __restrict__ c,
    float* __restrict__ out)
{
    int i = blockIdx.x * 256 + threadIdx.x;
    out[128 + i] = h[i];
    out[128 + Bn * Hn + i] = c[i];
}

__global__ __launch_bounds__(64) void classifier(
    const float* __restrict__ h, const float* __restrict__ Vw,
    const float* __restrict__ Vb, float* __restrict__ out)
{
    int bid = blockIdx.x;
    int b = bid >> 1, n = bid & 1;
    int lane = threadIdx.x;
    float sum = 0.f;
    for (int k = lane; k < Hn; k += 64)
        sum += h[b * Hn + k] * Vw[n * Hn + k];
    #pragma unroll
    for (int off = 32; off > 0; off >>= 1)
        sum += __shfl_down(sum, off, 64);
    if (lane == 0)
        out[b * 2 + n] = sum + Vb[n];
}

// ======================= fallback (round-1 proven path) =======================

#define KT 128
#define KTP 132

__global__ __launch_bounds__(256) void lstm_step_fb(
    const int* __restrict__ x, const float* __restrict__ emb,
    const float* __restrict__ Wxi, const float* __restrict__ Wxf,
    const float* __restrict__ Wxg, const float* __restrict__ Wxo,
    const float* __restrict__ bi, const float* __restrict__ bf,
    const float* __restrict__ bg, const float* __restrict__ bo,
    const float* __restrict__ Whi, const float* __restrict__ Whf,
    const float* __restrict__ Whg, const float* __restrict__ Who,
    const float* __restrict__ h_in, const float* __restrict__ c_in,
    float* __restrict__ h_out, float* __restrict__ c_out, int s)
{
    __shared__ float sh[Bn][KTP];
    __shared__ float sw[16][KTP];
    const int tid = threadIdx.x;
    const int b = tid >> 2, j = tid & 3;
    const int cb = blockIdx.x * 4, col = cb + j;
    float acc0 = 0.f, acc1 = 0.f, acc2 = 0.f, acc3 = 0.f;

    for (int k0 = 0; k0 < En; k0 += KT) {
        for (int i = tid; i < Bn * (KT / 4); i += 256) {
            int bl = i >> 5, k4 = (i & 31) << 2;
            int tok = x[bl * Sn + s];
            *reinterpret_cast<float4*>(&sh[bl][k4]) =
                *reinterpret_cast<const float4*>(&emb[(size_t)tok * En + k0 + k4]);
        }
        for (int i = tid; i < 16 * (KT / 4); i += 256) {
            int r = i >> 5, k4 = (i & 31) << 2;
            const float* Wg = (r < 8) ? ((r < 4) ? Wxi : Wxf)
                                      : ((r < 12) ? Wxg : Wxo);
            *reinterpret_cast<float4*>(&sw[r][k4]) =
                *reinterpret_cast<const float4*>(&Wg[(size_t)(cb + (r & 3)) * En + k0 + k4]);
        }
        __syncthreads();
        #pragma unroll 8
        for (int k = 0; k < KT; k += 4) {
            float4 hv = *reinterpret_cast<const float4*>(&sh[b][k]);
            float4 w0 = *reinterpret_cast<const float4*>(&sw[j][k]);
            float4 w1 = *reinterpret_cast<const float4*>(&sw[4 + j][k]);
            float4 w2 = *reinterpret_cast<const float4*>(&sw[8 + j][k]);
            float4 w3 = *reinterpret_cast<const float4*>(&sw[12 + j][k]);
            acc0 += hv.x*w0.x + hv.y*w0.y + hv.z*w0.z + hv.w*w0.w;
            acc1 += hv.x*w1.x + hv.y*w1.y + hv.z*w1.z + hv.w*w1.w;
            acc2 += hv.x*w2.x + hv.y*w2.y + hv.z*w2.z + hv.w*w2.w;
            acc3 += hv.x*w3.x + hv.y*w3.y + hv.z*w3.z + hv.w*w3.w;
        }
        __syncthreads();
    }
    for (int k0 = 0; k0 < Hn; k0 += KT) {
        for (int i = tid; i < Bn * (KT / 4); i += 256) {
            int bl = i >> 5, k4 = (i & 31) << 2;
            *reinterpret_cast<float4*>(&sh[bl][k4]) =
                *reinterpret_cast<const float4*>(&h_in[(size_t)bl * Hn + k0 + k4]);
        }
        for (int i = tid; i < 16 * (KT / 4); i += 256) {
            int r = i >> 5, k4 = (i & 31) << 2;
            const float* Wg = (r < 8) ? ((r < 4) ? Whi : Whf)
                                      : ((r < 12) ? Whg : Who);
            *reinterpret_cast<float4*>(&sw[r][k4]) =
                *reinterpret_cast<const float4*>(&Wg[(size_t)(cb + (r & 3)) * Hn + k0 + k4]);
        }
        __syncthreads();
        #pragma unroll 8
        for (int k = 0; k < KT; k += 4) {
            float4 hv = *reinterpret_cast<const float4*>(&sh[b][k]);
            float4 w0 = *reinterpret_cast<const float4*>(&sw[j][k]);
            float4 w1 = *reinterpret_cast<const float4*>(&sw[4 + j][k]);
            float4 w2 = *reinterpret_cast<const float4*>(&sw[8 + j][k]);
            float4 w3 = *reinterpret_cast<const float4*>(&sw[12 + j][k]);
            acc0 += hv.x*w0.x + hv.y*w0.y + hv.z*w0.z + hv.w*w0.w;
            acc1 += hv.x*w1.x + hv.y*w1.y + hv.z*w1.z + hv.w*w1.w;
            acc2 += hv.x*w2.x + hv.y*w2.y + hv.z*w2.z + hv.w*w2.w;
            acc3 += hv.x*w3.x + hv.y*w3.y + hv.z*w3.z + hv.w*w3.w;
        }
        __syncthreads();
    }
    acc0 += bi[col]; acc1 += bf[col]; acc2 += bg[col]; acc3 += bo[col];
    float it = 1.f / (1.f + expf(-acc0));
    float ft = 1.f / (1.f + expf(-acc1));
    float gt = tanhf(acc2);
    float ot = 1.f / (1.f + expf(-acc3));
    float cn = ft * c_in[b * Hn + col] + it * gt;
    c_out[b * Hn + col] = cn;
    h_out[b * Hn + col] = ot * tanhf(cn);
}

// ======================= launcher =======================

extern "C" void kernel_launch(void* const* d_in, const int* in_sizes, int n_in,
                              void* d_out, int out_size, void* d_ws, size_t ws_size,
                              hipStream_t stream) {
    const int*   x   = (const int*)  d_in[0];
    const float* emb = (const float*)d_in[1];
    const float* Wxi = (const float*)d_in[2];
    const float* bi  = (const float*)d_in[3];
    const float* Whi = (const float*)d_in[4];
    const float* Wxf = (const float*)d_in[5];
    const float* bf  = (const float*)d_in[6];
    const float* Whf = (const float*)d_in[7];
    const float* Wxg = (const float*)d_in[8];
    const float* bg  = (const float*)d_in[9];
    const float* Whg = (const float*)d_in[10];
    const float* Wxo = (const float*)d_in[11];
    const float* bo  = (const float*)d_in[12];
    const float* Who = (const float*)d_in[13];
    const float* Vw  = (const float*)d_in[14];
    const float* Vb  = (const float*)d_in[15];
    float* out = (float*)d_out;

    // ws layout (bytes):
    //   [hF: 2 x 128KB][c: 256KB][h: 256KB][eF: 32MB][wHi: 12MB][wLo: 12MB]
    const size_t szHF  = (size_t)2 * 32 * 4 * 64 * 8 * sizeof(f16);     // 256 KB
    const size_t szC   = (size_t)Bn * Hn * sizeof(float);               // 256 KB
    const size_t szH   = szC;                                           // 256 KB
    const size_t szEF  = (size_t)Sn * 16 * 4 * 64 * 8 * sizeof(f16);    // 32 MB
    const size_t szWp  = (size_t)4 * 64 * 48 * 64 * 8 * sizeof(f16);    // 12 MB
    const size_t need  = szHF + szC + szH + szEF + 2 * szWp;

    if (ws_size >= need) {
        char* base = (char*)d_ws;
        f16*   hF  = (f16*)base;                       base += szHF;
        float* c   = (float*)base;                     base += szC;
        float* h   = (float*)base;                     base += szH;
        f16*   eF  = (f16*)base;                       base += szEF;
        f16*   wHi = (f16*)base;                       base += szWp;
        f16*   wLo = (f16*)base;

        // zero hF (both buffers) + c  (they are adjacent at ws start)
        hipMemsetAsync(d_ws, 0, szHF + szC, stream);

        wpack_kernel<<<dim3(3072), dim3(256), 0, stream>>>(
            Whi, Whf, Whg, Who, Wxi, Wxf, Wxg, Wxo, wHi, wLo);
        epack_kernel<<<dim3(8192), dim3(256), 0, stream>>>(x, emb, eF);

        const size_t hfBuf = (size_t)32 * 4 * 64 * 8;   // halves per buffer
        for (int s = 0; s < Sn; ++s) {
            const f16* hin  = hF + (s & 1) * hfBuf;
            f16*       hout = hF + ((s + 1) & 1) * hfBuf;
            step_kernel<<<dim3(64), dim3(512), 0, stream>>>(
                (const half8*)hin, hout, (const half8*)eF,
                (const half8*)wHi, (const half8*)wLo,
                bi, bf, bg, bo, c, h, s);
        }
        copy_hc<<<dim3(Bn * Hn / 256), dim3(256), 0, stream>>>(h, c, out);
        classifier<<<dim3(Bn * 2), dim3(64), 0, stream>>>(h, Vw, Vb, out);
    } else {
        float* hA = (float*)d_ws;
        float* cA = hA + Bn * Hn;
        float* hB = cA + Bn * Hn;
        float* cB = hB + Bn * Hn;
        hipMemsetAsync(d_ws, 0, (size_t)2 * Bn * Hn * sizeof(float), stream);
        for (int s = 0; s < Sn; ++s) {
            const float* hi = (s & 1) ? hB : hA;
            const float* ci = (s & 1) ? cB : cA;
            float* ho = (s & 1) ? hA : hB;
            float* co = (s & 1) ? cA : cB;
            lstm_step_fb<<<dim3(Hn / 4), dim3(256), 0, stream>>>(
                x, emb, Wxi, Wxf, Wxg, Wxo, bi, bf, bg, bo,
                Whi, Whf, Whg, Who, hi, ci, ho, co, s);
        }
        copy_hc<<<dim3(Bn * Hn / 256), dim3(256), 0, stream>>>(hA, cA, out);
        classifier<<<dim3(Bn * 2), dim3(64), 0, stream>>>(hA, Vw, Vb, out);
    }
}

// Round 4
// 5818.091 us; speedup vs baseline: 6.2991x; 1.4301x over previous
//
#include <hip/hip_runtime.h>
#include <math.h>

#define Bn 64
#define Hn 1024
#define En 512
#define Sn 512

typedef _Float16 f16;
typedef _Float16 half8 __attribute__((ext_vector_type(8)));
typedef float f32x4 __attribute__((ext_vector_type(4)));

// ============================================================================
// Fragment layouts (gfx950 mfma_f32_16x16x32_f16, HW-verified):
//   A[m][k]: m = lane&15, k = (lane>>4)*8 + j
//   B[k][n]: n = lane&15, k = (lane>>4)*8 + j
//   C/D[m][n]: n = lane&15, m = (lane>>4)*4 + reg
//
// hF (A-side, f16): [(kc*4 + mt)*64 + lane]*8+j ; value z[b=mt*16+(lane&15)]
//   [k=kc*32+(lane>>4)*8+j], kc 0..31 (h only).
// eF (A-side, f16): [s][ (kc2*4+mt)*64+lane ]*8+j over e-k 0..511.
// whHi/whLo (B-side): [((g*64+bb)*32 + kc)*64 + lane]*8+j = Wh_g[u=bb*16+
//   (lane&15)][k=kc*32+(lane>>4)*8+j];  lo scaled x2048.
// wxHi/wxLo: [(nt*16 + kc)*64 + lane]*8+j, nt = g*64+bb, k over 0..511.
// gx ring: [sc][b][4096] f32, sc = s & 63.
// ============================================================================

__global__ __launch_bounds__(256) void whpack_kernel(
    const float* __restrict__ Whi_, const float* __restrict__ Whf_,
    const float* __restrict__ Whg_, const float* __restrict__ Who_,
    f16* __restrict__ wHi, f16* __restrict__ wLo)
{
    int t = blockIdx.x * 256 + threadIdx.x;   // 524288 = 4*64*32*64
    int lane = t & 63;
    int rest = t >> 6;
    int kc = rest & 31;
    int gbb = rest >> 5;
    int g = gbb >> 6, bb = gbb & 63;
    int u = bb * 16 + (lane & 15);
    int k = kc * 32 + ((lane >> 4) << 3);
    const float* Wh = (g == 0 ? Whi_ : g == 1 ? Whf_ : g == 2 ? Whg_ : Who_);
    const float* src = Wh + (size_t)u * Hn + k;
    float4 v0 = ((const float4*)src)[0];
    float4 v1 = ((const float4*)src)[1];
    float w[8] = {v0.x, v0.y, v0.z, v0.w, v1.x, v1.y, v1.z, v1.w};
    #pragma unroll
    for (int j = 0; j < 8; ++j) {
        f16 hi = (f16)w[j];
        float lo = (w[j] - (float)hi) * 2048.0f;
        wHi[(size_t)t * 8 + j] = hi;
        wLo[(size_t)t * 8 + j] = (f16)lo;
    }
}

__global__ __launch_bounds__(256) void wxpack_kernel(
    const float* __restrict__ Wxi_, const float* __restrict__ Wxf_,
    const float* __restrict__ Wxg_, const float* __restrict__ Wxo_,
    f16* __restrict__ wHi, f16* __restrict__ wLo)
{
    int t = blockIdx.x * 256 + threadIdx.x;   // 262144 = 256*16*64
    int lane = t & 63;
    int rest = t >> 6;
    int kc = rest & 15;
    int nt = rest >> 4;                        // g*64+bb
    int g = nt >> 6;
    int u = (nt & 63) * 16 + (lane & 15);
    int k = kc * 32 + ((lane >> 4) << 3);
    const float* Wx = (g == 0 ? Wxi_ : g == 1 ? Wxf_ : g == 2 ? Wxg_ : Wxo_);
    const float* src = Wx + (size_t)u * En + k;
    float4 v0 = ((const float4*)src)[0];
    float4 v1 = ((const float4*)src)[1];
    float w[8] = {v0.x, v0.y, v0.z, v0.w, v1.x, v1.y, v1.z, v1.w};
    #pragma unroll
    for (int j = 0; j < 8; ++j) {
        f16 hi = (f16)w[j];
        float lo = (w[j] - (float)hi) * 2048.0f;
        wHi[(size_t)t * 8 + j] = hi;
        wLo[(size_t)t * 8 + j] = (f16)lo;
    }
}

__global__ __launch_bounds__(256) void epack_kernel(
    const int* __restrict__ x, const float* __restrict__ emb,
    f16* __restrict__ eF)
{
    int t = blockIdx.x * 256 + threadIdx.x;   // 2097152 = 512*16*4*64
    int lane = t & 63;
    int q = t >> 6;
    int mt = q & 3; q >>= 2;
    int kc2 = q & 15;
    int s = q >> 4;
    int b = mt * 16 + (lane & 15);
    int tok = x[b * Sn + s];
    int k = kc2 * 32 + ((lane >> 4) << 3);
    const float* src = emb + (size_t)tok * En + k;
    float4 v0 = ((const float4*)src)[0];
    float4 v1 = ((const float4*)src)[1];
    f16* dst = eF + (size_t)t * 8;
    dst[0] = (f16)v0.x; dst[1] = (f16)v0.y; dst[2] = (f16)v0.z; dst[3] = (f16)v0.w;
    dst[4] = (f16)v1.x; dst[5] = (f16)v1.y; dst[6] = (f16)v1.z; dst[7] = (f16)v1.w;
}

// gx[sc][b][col] = e_s[b] . Wx[col] for 64 steps of one chunk.
// grid 1024 = 64(sc) x 16(ng), 256 threads; wave handles 4 n-tiles seq.
__global__ __launch_bounds__(256) void gx_chunk_kernel(
    const half8* __restrict__ eF,
    const half8* __restrict__ wxHi, const half8* __restrict__ wxLo,
    float* __restrict__ gx, int chunk)
{
    int sc = blockIdx.x >> 4;
    int ng = blockIdx.x & 15;
    int s  = chunk * 64 + sc;
    int lane = threadIdx.x & 63, w = threadIdx.x >> 6;
    const half8* eFs = eF + (size_t)s * (16 * 4 * 64) + lane;

    for (int nti = 0; nti < 4; ++nti) {
        int nt = ng * 16 + w * 4 + nti;
        f32x4 aH[4], aL[4];
        #pragma unroll
        for (int mt = 0; mt < 4; ++mt) { aH[mt] = (f32x4)0.0f; aL[mt] = (f32x4)0.0f; }
        const half8* bHi = wxHi + (size_t)(nt * 16) * 64 + lane;
        const half8* bLo = wxLo + (size_t)(nt * 16) * 64 + lane;
        for (int kc = 0; kc < 16; ++kc) {
            half8 bh = bHi[(size_t)kc * 64];
            half8 bl = bLo[(size_t)kc * 64];
            #pragma unroll
            for (int mt = 0; mt < 4; ++mt) {
                half8 a = eFs[(size_t)(kc * 4 + mt) * 64];
                aH[mt] = __builtin_amdgcn_mfma_f32_16x16x32_f16(a, bh, aH[mt], 0, 0, 0);
                aL[mt] = __builtin_amdgcn_mfma_f32_16x16x32_f16(a, bl, aL[mt], 0, 0, 0);
            }
        }
        float* g0 = gx + (size_t)sc * Bn * 4096 + nt * 16 + (lane & 15);
        #pragma unroll
        for (int mt = 0; mt < 4; ++mt) {
            #pragma unroll
            for (int r = 0; r < 4; ++r) {
                int b = mt * 16 + ((lane >> 4) << 2) + r;
                g0[(size_t)b * 4096] = aH[mt][r] + aL[mt][r] * (1.0f / 2048.0f);
            }
        }
    }
}

// Serial step: grid 64 x 1024. Block bb owns units [bb*16,+16) x 4 gates.
// Wave wv: g = wv&3, kq = wv>>2 (K split 4-way), reduce via LDS, fused cell.
template<bool USE_GX>
__global__ __launch_bounds__(1024) void step_kernel(
    const half8* __restrict__ hFin, f16* __restrict__ hFout,
    const half8* __restrict__ eF,
    const half8* __restrict__ whHi, const half8* __restrict__ whLo,
    const half8* __restrict__ wxHi, const half8* __restrict__ wxLo,
    const float* __restrict__ gx,
    const float* __restrict__ bi, const float* __restrict__ bf,
    const float* __restrict__ bg, const float* __restrict__ bo,
    float* __restrict__ c, float* __restrict__ hOut, int s)
{
    __shared__ float pre[4][4][64][17];   // [kq][g][b][u] padded, ~68 KB

    const int tid  = threadIdx.x;
    const int lane = tid & 63;
    const int wv   = tid >> 6;
    const int g    = wv & 3;
    const int kq   = wv >> 2;
    const int bb   = blockIdx.x;

    f32x4 aH[4], aL[4];
    #pragma unroll
    for (int mt = 0; mt < 4; ++mt) { aH[mt] = (f32x4)0.0f; aL[mt] = (f32x4)0.0f; }

    if (USE_GX) {
        // K = 1024 (h only), 8 kc per wave
        const half8* bh0 = whHi + ((size_t)((g * 64 + bb) * 32 + kq * 8)) * 64 + lane;
        const half8* bl0 = whLo + ((size_t)((g * 64 + bb) * 32 + kq * 8)) * 64 + lane;
        const half8* a0  = hFin + (size_t)(kq * 8 * 4) * 64 + lane;
        for (int i = 0; i < 8; ++i) {
            half8 bh = bh0[(size_t)i * 64];
            half8 bl = bl0[(size_t)i * 64];
            #pragma unroll
            for (int mt = 0; mt < 4; ++mt) {
                half8 a = a0[(size_t)(i * 4 + mt) * 64];
                aH[mt] = __builtin_amdgcn_mfma_f32_16x16x32_f16(a, bh, aH[mt], 0, 0, 0);
                aL[mt] = __builtin_amdgcn_mfma_f32_16x16x32_f16(a, bl, aL[mt], 0, 0, 0);
            }
        }
    } else {
        // K = 1536 combined, 12 kc per wave
        const half8* eFs = eF + (size_t)s * (16 * 4 * 64) + lane;
        for (int i = 0; i < 12; ++i) {
            int kc = kq * 12 + i;
            const half8 *bhp, *blp, *ap;
            if (kc < 32) {
                bhp = whHi + ((size_t)((g * 64 + bb) * 32 + kc)) * 64 + lane;
                blp = whLo + ((size_t)((g * 64 + bb) * 32 + kc)) * 64 + lane;
                ap  = hFin + (size_t)(kc * 4) * 64 + lane;
            } else {
                int kcx = kc - 32;
                bhp = wxHi + ((size_t)((g * 64 + bb) * 16 + kcx)) * 64 + lane;
                blp = wxLo + ((size_t)((g * 64 + bb) * 16 + kcx)) * 64 + lane;
                ap  = eFs + (size_t)(kcx * 4) * 64;
            }
            half8 bh = *bhp, bl = *blp;
            #pragma unroll
            for (int mt = 0; mt < 4; ++mt) {
                half8 a = ap[(size_t)mt * 64];
                aH[mt] = __builtin_amdgcn_mfma_f32_16x16x32_f16(a, bh, aH[mt], 0, 0, 0);
                aL[mt] = __builtin_amdgcn_mfma_f32_16x16x32_f16(a, bl, aL[mt], 0, 0, 0);
            }
        }
    }

    #pragma unroll
    for (int mt = 0; mt < 4; ++mt) {
        #pragma unroll
        for (int r = 0; r < 4; ++r) {
            int bidx = mt * 16 + ((lane >> 4) << 2) + r;
            pre[kq][g][bidx][lane & 15] = aH[mt][r] + aL[mt][r] * (1.0f / 2048.0f);
        }
    }
    __syncthreads();

    if (tid < 1024) {
        int b = tid >> 4, u = tid & 15;
        int col = bb * 16 + u;
        float si = pre[0][0][b][u] + pre[1][0][b][u] + pre[2][0][b][u] + pre[3][0][b][u] + bi[col];
        float sf = pre[0][1][b][u] + pre[1][1][b][u] + pre[2][1][b][u] + pre[3][1][b][u] + bf[col];
        float sg = pre[0][2][b][u] + pre[1][2][b][u] + pre[2][2][b][u] + pre[3][2][b][u] + bg[col];
        float so = pre[0][3][b][u] + pre[1][3][b][u] + pre[2][3][b][u] + pre[3][3][b][u] + bo[col];
        if (USE_GX) {
            const float* gr = gx + ((size_t)(s & 63) * Bn + b) * 4096;
            si += gr[col]; sf += gr[1024 + col]; sg += gr[2048 + col]; so += gr[3072 + col];
        }
        float it = 1.f / (1.f + expf(-si));
        float ft = 1.f / (1.f + expf(-sf));
        float gt = tanhf(sg);
        float ot = 1.f / (1.f + expf(-so));
        int gi = b * Hn + col;
        float cn = ft * c[gi] + it * gt;
        c[gi] = cn;
        float hn = ot * tanhf(cn);
        hOut[gi] = hn;
        int kc = col >> 5, dk = col & 31;
        int lp = ((dk >> 3) << 4) | (b & 15);
        int mtp = b >> 4;
        hFout[((size_t)(kc * 4 + mtp) * 64 + lp) * 8 + (dk & 7)] = (f16)hn;
    }
}

// ---- tail ----
__global__ __launch_bounds__(256) void copy_hc(
    const float* __restrict__ h, const float* __restrict__ c,
    float* __restrict__ out)
{
    int i = blockIdx.x * 256 + threadIdx.x;
    out[128 + i] = h[i];
    out[128 + Bn * Hn + i] = c[i];
}

__global__ __launch_bounds__(64) void classifier(
    const float* __restrict__ h, const float* __restrict__ Vw,
    const float* __restrict__ Vb, float* __restrict__ out)
{
    int bid = blockIdx.x;
    int b = bid >> 1, n = bid & 1;
    int lane = threadIdx.x;
    float sum = 0.f;
    for (int k = lane; k < Hn; k += 64)
        sum += h[b * Hn + k] * Vw[n * Hn + k];
    #pragma unroll
    for (int off = 32; off > 0; off >>= 1)
        sum += __shfl_down(sum, off, 64);
    if (lane == 0)
        out[b * 2 + n] = sum + Vb[n];
}

// ======================= fallback (round-1 proven path) =======================

#define KT 128
#define KTP 132

__global__ __launch_bounds__(256) void lstm_step_fb(
    const int* __restrict__ x, const float* __restrict__ emb,
    const float* __restrict__ Wxi, const float* __restrict__ Wxf,
    const float* __restrict__ Wxg, const float* __restrict__ Wxo,
    const float* __restrict__ bi, const float* __restrict__ bf,
    const float* __restrict__ bg, const float* __restrict__ bo,
    const float* __restrict__ Whi, const float* __restrict__ Whf,
    const float* __restrict__ Whg, const float* __restrict__ Who,
    const float* __restrict__ h_in, const float* __restrict__ c_in,
    float* __restrict__ h_out, float* __restrict__ c_out, int s)
{
    __shared__ float sh[Bn][KTP];
    __shared__ float sw[16][KTP];
    const int tid = threadIdx.x;
    const int b = tid >> 2, j = tid & 3;
    const int cb = blockIdx.x * 4, col = cb + j;
    float acc0 = 0.f, acc1 = 0.f, acc2 = 0.f, acc3 = 0.f;

    for (int k0 = 0; k0 < En; k0 += KT) {
        for (int i = tid; i < Bn * (KT / 4); i += 256) {
            int bl = i >> 5, k4 = (i & 31) << 2;
            int tok = x[bl * Sn + s];
            *reinterpret_cast<float4*>(&sh[bl][k4]) =
                *reinterpret_cast<const float4*>(&emb[(size_t)tok * En + k0 + k4]);
        }
        for (int i = tid; i < 16 * (KT / 4); i += 256) {
            int r = i >> 5, k4 = (i & 31) << 2;
            const float* Wg = (r < 8) ? ((r < 4) ? Wxi : Wxf)
                                      : ((r < 12) ? Wxg : Wxo);
            *reinterpret_cast<float4*>(&sw[r][k4]) =
                *reinterpret_cast<const float4*>(&Wg[(size_t)(cb + (r & 3)) * En + k0 + k4]);
        }
        __syncthreads();
        #pragma unroll 8
        for (int k = 0; k < KT; k += 4) {
            float4 hv = *reinterpret_cast<const float4*>(&sh[b][k]);
            float4 w0 = *reinterpret_cast<const float4*>(&sw[j][k]);
            float4 w1 = *reinterpret_cast<const float4*>(&sw[4 + j][k]);
            float4 w2 = *reinterpret_cast<const float4*>(&sw[8 + j][k]);
            float4 w3 = *reinterpret_cast<const float4*>(&sw[12 + j][k]);
            acc0 += hv.x*w0.x + hv.y*w0.y + hv.z*w0.z + hv.w*w0.w;
            acc1 += hv.x*w1.x + hv.y*w1.y + hv.z*w1.z + hv.w*w1.w;
            acc2 += hv.x*w2.x + hv.y*w2.y + hv.z*w2.z + hv.w*w2.w;
            acc3 += hv.x*w3.x + hv.y*w3.y + hv.z*w3.z + hv.w*w3.w;
        }
        __syncthreads();
    }
    for (int k0 = 0; k0 < Hn; k0 += KT) {
        for (int i = tid; i < Bn * (KT / 4); i += 256) {
            int bl = i >> 5, k4 = (i & 31) << 2;
            *reinterpret_cast<float4*>(&sh[bl][k4]) =
                *reinterpret_cast<const float4*>(&h_in[(size_t)bl * Hn + k0 + k4]);
        }
        for (int i = tid; i < 16 * (KT / 4); i += 256) {
            int r = i >> 5, k4 = (i & 31) << 2;
            const float* Wg = (r < 8) ? ((r < 4) ? Whi : Whf)
                                      : ((r < 12) ? Whg : Who);
            *reinterpret_cast<float4*>(&sw[r][k4]) =
                *reinterpret_cast<const float4*>(&Wg[(size_t)(cb + (r & 3)) * Hn + k0 + k4]);
        }
        __syncthreads();
        #pragma unroll 8
        for (int k = 0; k < KT; k += 4) {
            float4 hv = *reinterpret_cast<const float4*>(&sh[b][k]);
            float4 w0 = *reinterpret_cast<const float4*>(&sw[j][k]);
            float4 w1 = *reinterpret_cast<const float4*>(&sw[4 + j][k]);
            float4 w2 = *reinterpret_cast<const float4*>(&sw[8 + j][k]);
            float4 w3 = *reinterpret_cast<const float4*>(&sw[12 + j][k]);
            acc0 += hv.x*w0.x + hv.y*w0.y + hv.z*w0.z + hv.w*w0.w;
            acc1 += hv.x*w1.x + hv.y*w1.y + hv.z*w1.z + hv.w*w1.w;
            acc2 += hv.x*w2.x + hv.y*w2.y + hv.z*w2.z + hv.w*w2.w;
            acc3 += hv.x*w3.x + hv.y*w3.y + hv.z*w3.z + hv.w*w3.w;
        }
        __syncthreads();
    }
    acc0 += bi[col]; acc1 += bf[col]; acc2 += bg[col]; acc3 += bo[col];
    float it = 1.f / (1.f + expf(-acc0));
    float ft = 1.f / (1.f + expf(-acc1));
    float gt = tanhf(acc2);
    float ot = 1.f / (1.f + expf(-acc3));
    float cn = ft * c_in[b * Hn + col] + it * gt;
    c_out[b * Hn + col] = cn;
    h_out[b * Hn + col] = ot * tanhf(cn);
}

// ======================= launcher =======================

extern "C" void kernel_launch(void* const* d_in, const int* in_sizes, int n_in,
                              void* d_out, int out_size, void* d_ws, size_t ws_size,
                              hipStream_t stream) {
    const int*   x   = (const int*)  d_in[0];
    const float* emb = (const float*)d_in[1];
    const float* Wxi = (const float*)d_in[2];
    const float* bi  = (const float*)d_in[3];
    const float* Whi = (const float*)d_in[4];
    const float* Wxf = (const float*)d_in[5];
    const float* bf  = (const float*)d_in[6];
    const float* Whf = (const float*)d_in[7];
    const float* Wxg = (const float*)d_in[8];
    const float* bg  = (const float*)d_in[9];
    const float* Whg = (const float*)d_in[10];
    const float* Wxo = (const float*)d_in[11];
    const float* bo  = (const float*)d_in[12];
    const float* Who = (const float*)d_in[13];
    const float* Vw  = (const float*)d_in[14];
    const float* Vb  = (const float*)d_in[15];
    float* out = (float*)d_out;

    // ws layout: [hF 256K][c 256K][h 256K][eF 32M][whHi 8M][whLo 8M]
    //            [wxHi 4M][wxLo 4M][gx 64M]
    const size_t szHF  = (size_t)2 * 32 * 4 * 64 * 8 * sizeof(f16);   // 256 KB
    const size_t szC   = (size_t)Bn * Hn * sizeof(float);             // 256 KB
    const size_t szEF  = (size_t)Sn * 16 * 4 * 64 * 8 * sizeof(f16);  // 32 MB
    const size_t szWh  = (size_t)4 * 64 * 32 * 64 * 8 * sizeof(f16);  // 8 MB
    const size_t szWx  = (size_t)256 * 16 * 64 * 8 * sizeof(f16);     // 4 MB
    const size_t szGx  = (size_t)64 * Bn * 4096 * sizeof(float);      // 64 MB
    const size_t need2 = szHF + 2 * szC + szEF + 2 * szWh + 2 * szWx;
    const size_t need1 = need2 + szGx;

    if (ws_size >= need2) {
        const bool useGx = (ws_size >= need1);
        char* base = (char*)d_ws;
        f16*   hF   = (f16*)base;   base += szHF;
        float* c    = (float*)base; base += szC;
        float* h    = (float*)base; base += szC;
        f16*   eF   = (f16*)base;   base += szEF;
        f16*   whHi = (f16*)base;   base += szWh;
        f16*   whLo = (f16*)base;   base += szWh;
        f16*   wxHi = (f16*)base;   base += szWx;
        f16*   wxLo = (f16*)base;   base += szWx;
        float* gx   = (float*)base;

        hipMemsetAsync(d_ws, 0, szHF + szC, stream);   // hF both bufs + c
        whpack_kernel<<<dim3(2048), dim3(256), 0, stream>>>(
            Whi, Whf, Whg, Who, whHi, whLo);
        wxpack_kernel<<<dim3(1024), dim3(256), 0, stream>>>(
            Wxi, Wxf, Wxg, Wxo, wxHi, wxLo);
        epack_kernel<<<dim3(8192), dim3(256), 0, stream>>>(x, emb, eF);

        const size_t hfBuf = (size_t)32 * 4 * 64 * 8;
        if (useGx) {
            for (int chunk = 0; chunk < 8; ++chunk) {
                gx_chunk_kernel<<<dim3(1024), dim3(256), 0, stream>>>(
                    (const half8*)eF, (const half8*)wxHi, (const half8*)wxLo,
                    gx, chunk);
                for (int sc = 0; sc < 64; ++sc) {
                    int s = chunk * 64 + sc;
                    const f16* hin  = hF + (s & 1) * hfBuf;
                    f16*       hout = hF + ((s + 1) & 1) * hfBuf;
                    step_kernel<true><<<dim3(64), dim3(1024), 0, stream>>>(
                        (const half8*)hin, hout, (const half8*)eF,
                        (const half8*)whHi, (const half8*)whLo,
                        (const half8*)wxHi, (const half8*)wxLo,
                        gx, bi, bf, bg, bo, c, h, s);
                }
            }
        } else {
            for (int s = 0; s < Sn; ++s) {
                const f16* hin  = hF + (s & 1) * hfBuf;
                f16*       hout = hF + ((s + 1) & 1) * hfBuf;
                step_kernel<false><<<dim3(64), dim3(1024), 0, stream>>>(
                    (const half8*)hin, hout, (const half8*)eF,
                    (const half8*)whHi, (const half8*)whLo,
                    (const half8*)wxHi, (const half8*)wxLo,
                    (const float*)nullptr, bi, bf, bg, bo, c, h, s);
            }
        }
        copy_hc<<<dim3(Bn * Hn / 256), dim3(256), 0, stream>>>(h, c, out);
        classifier<<<dim3(Bn * 2), dim3(64), 0, stream>>>(h, Vw, Vb, out);
    } else {
        float* hA = (float*)d_ws;
        float* cA = hA + Bn * Hn;
        float* hB = cA + Bn * Hn;
        float* cB = hB + Bn * Hn;
        hipMemsetAsync(d_ws, 0, (size_t)2 * Bn * Hn * sizeof(float), stream);
        for (int s = 0; s < Sn; ++s) {
            const float* hi = (s & 1) ? hB : hA;
            const float* ci = (s & 1) ? cB : cA;
            float* ho = (s & 1) ? hA : hB;
            float* co = (s & 1) ? cA : cB;
            lstm_step_fb<<<dim3(Hn / 4), dim3(256), 0, stream>>>(
                x, emb, Wxi, Wxf, Wxg, Wxo, bi, bf, bg, bo,
                Whi, Whf, Whg, Who, hi, ci, ho, co, s);
        }
        copy_hc<<<dim3(Bn * Hn / 256), dim3(256), 0, stream>>>(hA, cA, out);
        classifier<<<dim3(Bn * 2), dim3(64), 0, stream>>>(hA, Vw, Vb, out);
    }
}